// Round 9
// baseline (110.891 us; speedup 1.0000x reference)
//
#include <hip/hip_runtime.h>
#include <math.h>

// Problem constants
#define BATCH 1024
#define FEAT  512
#define NT    64
#define DDIM  1024          // CSETSIZE(64) * Nrf(4) * Nrf(4)

typedef __attribute__((ext_vector_type(8))) short  short8;
typedef __attribute__((ext_vector_type(4))) float  floatx4;

// ws layout (bytes):
//   A-image : 16 row-tiles x 8 k-tiles x 8 KB = 1,048,576
//   B-image : 32 col-tiles x 8 k-tiles x 8 KB = 2,097,152 (Dr/Di interleaved)
#define AIMG_OFF  0
#define BIMG_OFF  1048576

// fp32 -> bf16 round-to-nearest-even
__device__ __forceinline__ unsigned short bf16rne(float f) {
    unsigned int u = __float_as_uint(f);
    return (unsigned short)((u + 0x7fffu + ((u >> 16) & 1u)) >> 16);
}

__device__ __forceinline__ void gld16(const unsigned char* g, unsigned char* l) {
    __builtin_amdgcn_global_load_lds(
        (const __attribute__((address_space(1))) unsigned int*)g,
        (__attribute__((address_space(3))) unsigned int*)l, 16, 0, 0);
}

// Output layout (flat):
//   A_real : [0, BATCH*4096)   A_imag : [BATCH*4096, 2*BATCH*4096)
//   D_r_n  : 2*BATCH*4096 + [0, BATCH*1024)
//   D_i_n  : 2*BATCH*4096 + BATCH*1024 + [0, BATCH*1024)
//   CSet   : last 16384 floats

// ===========================================================================
// K0: short, uniform prep.
//  bid<256:      convert fp32 -> bf16 LDS-image tiles (8 KB = 64 rows x 64 k,
//                16B chunks XOR-swizzled c^(r&7)). B-image interleaves Dr/Di
//                per 16-col c-block.
//  bid 256..271: CSet pass-through.
// (theta moved into K1's fill blocks -- removes the straggler tail that gated
//  the K0->K1 boundary in r8.)
// ===========================================================================
__global__ __launch_bounds__(256) void k0_prep(
    const float* __restrict__ x,
    const float* __restrict__ W_Dr, const float* __restrict__ W_Di,
    const float* __restrict__ cset,
    unsigned char* __restrict__ ws, float* __restrict__ out)
{
    const int bid = blockIdx.x;
    const int tid = threadIdx.x;

    if (bid < 256) {
        unsigned short* aimg = (unsigned short*)(ws + AIMG_OFF);
        unsigned short* bimg = (unsigned short*)(ws + BIMG_OFF);
        const int gtid = bid * 256 + tid;   // 65536 threads
        for (int idx = gtid; idx < 196608; idx += 65536) {
            const float* src;
            unsigned short* dst;
            if (idx < 65536) {                 // A-image: x
                const int rt = idx >> 12, kb = (idx >> 9) & 7;
                const int r  = (idx >> 3) & 63, c = idx & 7;
                src = x + ((size_t)(rt * 64 + r) * FEAT + kb * 64 + c * 8);
                dst = aimg + ((rt * 8 + kb) * 4096 + r * 64 + ((c ^ (r & 7)) * 8));
            } else {                           // B-image: W_Dr/W_Di interleaved
                const int j  = idx - 65536;
                const int ct = j >> 12, kb = (j >> 9) & 7;
                const int n  = (j >> 3) & 63, c = j & 7;
                const int g = n >> 5, h = (n >> 4) & 1, pos = n & 15;
                const float* wrow =
                    (h ? W_Di : W_Dr) + (size_t)(ct * 32 + g * 16 + pos) * FEAT;
                src = wrow + kb * 64 + c * 8;
                dst = bimg + ((ct * 8 + kb) * 4096 + n * 64 + ((c ^ (n & 7)) * 8));
            }
            const float4 v0 = *(const float4*)src;
            const float4 v1 = *(const float4*)(src + 4);
            short8 o;
            o[0] = (short)bf16rne(v0.x); o[1] = (short)bf16rne(v0.y);
            o[2] = (short)bf16rne(v0.z); o[3] = (short)bf16rne(v0.w);
            o[4] = (short)bf16rne(v1.x); o[5] = (short)bf16rne(v1.y);
            o[6] = (short)bf16rne(v1.z); o[7] = (short)bf16rne(v1.w);
            *(short8*)dst = o;
        }
    } else {
        const int cb = bid - 256;              // 0..15
        const size_t base = (size_t)2 * BATCH * 4096 + (size_t)2 * BATCH * DDIM;
        ((float4*)(out + base))[cb * 256 + tid] = ((const float4*)cset)[cb * 256 + tid];
    }
}

// ===========================================================================
// K1, heterogeneous:
//  bid<512:       D-GEMM from images (rt=bid&15, ct=bid>>4). global_load_lds
//                 double-buffered, 1 barrier/64-K step; bias + per-row
//                 Frobenius norm epilogue, writes 2*D/V_F.  (r7/r8-verified)
//  bid 512..1535: A_real/A_imag fill for b = bid-512. theta computed IN-BLOCK:
//                 thread (t=tid>>2, q=tid&3) dots x[b]·W_A[t] over its k-quarter
//                 (32 float4 pairs, chunked 8-deep for VGPR), shfl-quad reduce,
//                 sincos at q==0 -> LDS, one barrier, then 32 KB diag stores.
// ===========================================================================
__global__ __launch_bounds__(256) void k1_main(
    const unsigned char* __restrict__ ws,
    const float* __restrict__ x,   const float* __restrict__ W_A,
    const float* __restrict__ b_A,
    const float* __restrict__ b_Dr, const float* __restrict__ b_Di,
    float* __restrict__ out)
{
    __shared__ __align__(16) unsigned char smem[32768];

    const int bid = blockIdx.x;
    const int tid = threadIdx.x;

    if (bid < 512) {
        // ---------------- D-GEMM from images ----------------
        const int rt   = bid & 15;
        const int ct   = bid >> 4;        // 0..31
        const int lane = tid & 63;
        const int wv   = tid >> 6;
        const int ln   = lane & 15;
        const int quad = lane >> 4;
        const int row0 = rt * 64;

        const unsigned char* Atiles = ws + AIMG_OFF + (size_t)rt * 8 * 8192;
        const unsigned char* Btiles = ws + BIMG_OFF + (size_t)ct * 8 * 8192;

        const int g0 = (wv * 2 + 0) * 1024;
        const int g1 = (wv * 2 + 1) * 1024;
        const int lo = lane * 16;

        floatx4 acc[4] = {{0,0,0,0},{0,0,0,0},{0,0,0,0},{0,0,0,0}};

        {   // prefetch kb=0 into buf 0
            unsigned char* La = smem;
            unsigned char* Lb = smem + 8192;
            gld16(Atiles + g0 + lo, La + g0);
            gld16(Atiles + g1 + lo, La + g1);
            gld16(Btiles + g0 + lo, Lb + g0);
            gld16(Btiles + g1 + lo, Lb + g1);
        }

        const int rowOffA = (wv * 16 + ln) * 128;
        const int swz = ln & 7;
        int cur = 0;

        #pragma unroll 1
        for (int kb = 0; kb < 8; ++kb) {
            __syncthreads();   // buf 'cur' staged (vmcnt drain); prev reads done
            if (kb < 7) {
                const unsigned char* At = Atiles + (kb + 1) * 8192;
                const unsigned char* Bt = Btiles + (kb + 1) * 8192;
                unsigned char* La = smem + (cur ^ 1) * 16384;
                unsigned char* Lb = La + 8192;
                gld16(At + g0 + lo, La + g0);
                gld16(At + g1 + lo, La + g1);
                gld16(Bt + g0 + lo, Lb + g0);
                gld16(Bt + g1 + lo, Lb + g1);
            }
            const unsigned char* La = smem + cur * 16384;
            const unsigned char* Lb = La + 8192;
            #pragma unroll
            for (int ks = 0; ks < 2; ++ks) {
                const int ca = ((ks * 4 + quad) ^ swz) * 16;
                const short8 a = *(const short8*)(La + rowOffA + ca);
                #pragma unroll
                for (int t = 0; t < 4; ++t) {
                    const short8 b = *(const short8*)(Lb + (t * 16 + ln) * 128 + ca);
                    acc[t] = __builtin_amdgcn_mfma_f32_16x16x32_bf16(a, b, acc[t], 0, 0, 0);
                }
            }
            cur ^= 1;
        }

        // epilogue: bias + per-row Frobenius norm (C/D: col=lane&15, row=quad*4+i)
        const size_t drn = (size_t)2 * BATCH * 4096;
        const size_t din = drn + (size_t)BATCH * DDIM;
        const int woff = ct * 32;
        #pragma unroll
        for (int p = 0; p < 2; ++p) {
            const int colg = woff + p * 16 + ln;
            const float br = b_Dr[colg];
            const float bi = b_Di[colg];
            float dr[4], di[4], ps[4];
            #pragma unroll
            for (int i = 0; i < 4; ++i) {
                dr[i] = acc[2 * p][i] + br;
                di[i] = acc[2 * p + 1][i] + bi;
                ps[i] = dr[i] * dr[i] + di[i] * di[i];
            }
            #pragma unroll
            for (int i = 0; i < 4; ++i) {
                ps[i] += __shfl_xor(ps[i], 1);
                ps[i] += __shfl_xor(ps[i], 2);
                ps[i] += __shfl_xor(ps[i], 4);
                ps[i] += __shfl_xor(ps[i], 8);
            }
            #pragma unroll
            for (int i = 0; i < 4; ++i) {
                const float scale = 2.0f / sqrtf(8.0f * ps[i]);
                const size_t row_g = (size_t)(row0 + wv * 16 + quad * 4 + i);
                out[drn + row_g * DDIM + colg] = dr[i] * scale;
                out[din + row_g * DDIM + colg] = di[i] * scale;
            }
        }
    } else {
        // ---------------- A-fill path (in-block theta) ----------------
        float* cosT = (float*)smem;
        float* sinT = cosT + NT;
        const int b = bid - 512;
        const int t = tid >> 2;          // antenna 0..63
        const int q = tid & 3;           // k-quarter phase

        // theta_t = sum_k x[b][k] * W_A[t][k]; this thread covers k = q*4+16i+j
        const float* wrow = W_A + (size_t)t * FEAT + q * 4;
        const float* xrow = x   + (size_t)b * FEAT + q * 4;
        float sum = 0.f;
        #pragma unroll 1
        for (int ch = 0; ch < 4; ++ch) {       // 4 chunks x 8 float4-pairs
            float4 wv4[8], xv4[8];
            #pragma unroll
            for (int i = 0; i < 8; ++i) {
                const int ko = (ch * 8 + i) * 16;
                wv4[i] = *(const float4*)(wrow + ko);
                xv4[i] = *(const float4*)(xrow + ko);
            }
            #pragma unroll
            for (int i = 0; i < 8; ++i)
                sum += wv4[i].x * xv4[i].x + wv4[i].y * xv4[i].y
                     + wv4[i].z * xv4[i].z + wv4[i].w * xv4[i].w;
        }
        sum += __shfl_xor(sum, 1);
        sum += __shfl_xor(sum, 2);             // quad now holds full dot
        if (q == 0) {
            float s, c;
            sincosf(sum + b_A[t], &s, &c);
            cosT[t] = c; sinT[t] = s;
        }
        __syncthreads();

        float* ar = out + (size_t)b * 4096;
        float* ai = out + (size_t)BATCH * 4096 + (size_t)b * 4096;
        #pragma unroll
        for (int it = 0; it < 4; ++it) {
            const int idx = tid + it * 256;   // float4 chunk 0..1023
            const int tt = idx >> 4;          // row in 64x64
            const int j0 = (idx & 15) * 4;    // first col of chunk
            float4 vr = {0.f, 0.f, 0.f, 0.f};
            float4 vi = {0.f, 0.f, 0.f, 0.f};
            if (tt >= j0 && tt < j0 + 4) {
                ((float*)&vr)[tt - j0] = cosT[tt];
                ((float*)&vi)[tt - j0] = sinT[tt];
            }
            ((float4*)ar)[idx] = vr;
            ((float4*)ai)[idx] = vi;
        }
    }
}

extern "C" void kernel_launch(void* const* d_in, const int* in_sizes, int n_in,
                              void* d_out, int out_size, void* d_ws, size_t ws_size,
                              hipStream_t stream) {
    const float* x    = (const float*)d_in[0];
    const float* W_A  = (const float*)d_in[1];
    const float* b_A  = (const float*)d_in[2];
    const float* W_Dr = (const float*)d_in[3];
    const float* b_Dr = (const float*)d_in[4];
    const float* W_Di = (const float*)d_in[5];
    const float* b_Di = (const float*)d_in[6];
    const float* CSet = (const float*)d_in[7];
    float* out = (float*)d_out;
    unsigned char* ws = (unsigned char*)d_ws;

    k0_prep<<<272, 256, 0, stream>>>(x, W_Dr, W_Di, CSet, ws, out);
    k1_main<<<1536, 256, 0, stream>>>(ws, x, W_A, b_A, b_Dr, b_Di, out);
}